// Round 5
// baseline (573.210 us; speedup 1.0000x reference)
//
#include <hip/hip_runtime.h>

typedef __bf16 bf16;
typedef __bf16 bf16x4 __attribute__((ext_vector_type(4)));
typedef __bf16 bf16x8 __attribute__((ext_vector_type(8)));
typedef float  fx4    __attribute__((ext_vector_type(4)));

#define MFMA16(a, b, c) __builtin_amdgcn_mfma_f32_16x16x32_bf16((a), (b), (c), 0, 0, 0)

// Problem constants: B=4, N=2048, E=768, H=8, D=96; M = B*N = 8192
// All user tensors are fp32 (verified round 4). Output fp32.

// ---------------------------------------------------------------------------
// x (fp32, 6291456 elems) -> bf16. 4 elems/thread.
// ---------------------------------------------------------------------------
__global__ __launch_bounds__(256)
void cvt_x_kernel(const float* __restrict__ x, bf16* __restrict__ xb) {
  const int i = (blockIdx.x * 256 + threadIdx.x) * 4;
  float4 v = *(const float4*)&x[i];
  bf16x4 o;
  o[0] = (bf16)v.x; o[1] = (bf16)v.y; o[2] = (bf16)v.z; o[3] = (bf16)v.w;
  *(bf16x4*)&xb[i] = o;
}

// ---------------------------------------------------------------------------
// GEMM: C[M,768] = A[M,768] @ W[768,768]^T + bias. A bf16, W/bias fp32.
// Tile 128x128, BK=32, 256 threads = 4 waves (2x2), 4x4 16x16x32 MFMAs/wave.
// TRANSV=1: write V transposed as Vt[(batch*768+o)][n] bf16.
// OUT32=1: store fp32 (final projection), else bf16.
// ---------------------------------------------------------------------------
template<int TRANSV, int OUT32>
__global__ __launch_bounds__(256)
void gemm_bt(const bf16* __restrict__ A, const float* __restrict__ W,
             const float* __restrict__ bias, void* __restrict__ Cv) {
  constexpr int K = 768;
  __shared__ __align__(16) bf16 As[128 * 32];
  __shared__ __align__(16) bf16 Bs[128 * 32];

  const int tid  = threadIdx.x;
  const int wave = tid >> 6;
  const int lane = tid & 63;
  const int l15  = lane & 15;
  const int q4   = lane >> 4;
  const int wr   = wave >> 1;
  const int wc   = wave & 1;
  const int rb0  = blockIdx.y * 128;
  const int cb0  = blockIdx.x * 128;

  fx4 acc[4][4];
#pragma unroll
  for (int i = 0; i < 4; i++)
#pragma unroll
    for (int j = 0; j < 4; j++) acc[i][j] = (fx4){0.f, 0.f, 0.f, 0.f};

  for (int k0 = 0; k0 < K; k0 += 32) {
    for (int c = tid; c < 512; c += 256) {
      const int row = c >> 2;
      const int kc  = (c & 3) << 3;
      *(uint4*)&As[row * 32 + kc] =
          *(const uint4*)&A[(size_t)(rb0 + row) * K + k0 + kc];
      const float* sb = W + (size_t)(cb0 + row) * K + k0 + kc;
      bf16x8 pb;
#pragma unroll
      for (int t = 0; t < 8; t++) pb[t] = (bf16)sb[t];
      *(bf16x8*)&Bs[row * 32 + kc] = pb;
    }
    __syncthreads();

    bf16x8 a[4], b[4];
#pragma unroll
    for (int i = 0; i < 4; i++)
      a[i] = *(const bf16x8*)&As[(wr * 64 + i * 16 + l15) * 32 + q4 * 8];
#pragma unroll
    for (int j = 0; j < 4; j++)
      b[j] = *(const bf16x8*)&Bs[(wc * 64 + j * 16 + l15) * 32 + q4 * 8];
#pragma unroll
    for (int i = 0; i < 4; i++)
#pragma unroll
      for (int j = 0; j < 4; j++)
        acc[i][j] = MFMA16(a[i], b[j], acc[i][j]);
    __syncthreads();
  }

  // Epilogue. C/D layout: col = lane&15, row = (lane>>4)*4 + reg.
  const int cb = cb0 + wc * 64;
  const int rb = rb0 + wr * 64;
#pragma unroll
  for (int j = 0; j < 4; j++) {
    const int o  = cb + j * 16 + l15;
    const float bj = bias[o];
#pragma unroll
    for (int i = 0; i < 4; i++) {
      const int r0 = rb + i * 16 + q4 * 4;
      if (TRANSV) {
        const int bb = r0 >> 11;
        const int n0 = r0 & 2047;
        bf16x4 pk;
#pragma unroll
        for (int r = 0; r < 4; r++) pk[r] = (bf16)(acc[i][j][r] + bj);
        *(bf16x4*)&((bf16*)Cv)[((size_t)(bb * 768 + o)) * 2048 + n0] = pk;
      } else if (OUT32) {
#pragma unroll
        for (int r = 0; r < 4; r++)
          ((float*)Cv)[(size_t)(r0 + r) * 768 + o] = acc[i][j][r] + bj;
      } else {
#pragma unroll
        for (int r = 0; r < 4; r++)
          ((bf16*)Cv)[(size_t)(r0 + r) * 768 + o] = (bf16)(acc[i][j][r] + bj);
      }
    }
  }
}

// ---------------------------------------------------------------------------
// Attention, softmax over HEADS (dim=1), / sqrt(768).
// TQ=16, TK=64. Grid = 4 batch * 128 qtiles = 512 blocks (2 blocks/CU).
// 512 threads = 8 waves; wave h owns head h.
// Ebuf strides: k=1, h=64, q=514 (pad: E-scatter lands 2 lanes/bank = free).
// V-fragments loaded at iteration top so their latency overlaps QK+scatter.
// AO aliases Q: block reads only its own 16 rows before the loop, writes
// only those rows after it.
// ---------------------------------------------------------------------------
__global__ __launch_bounds__(512, 4)
void attn_kernel(const bf16* Q, const bf16* __restrict__ Kb,
                 const bf16* __restrict__ Vt, bf16* AO) {
  __shared__ __align__(16) float Ebuf[16 * 514 + 32];   // ~33 KB
  __shared__ __align__(16) bf16  Pbuf[8 * 16 * 64];     // 16 KB

  const int tid  = threadIdx.x;
  const int h    = tid >> 6;
  const int lane = tid & 63;
  const int l15  = lane & 15;
  const int q4   = lane >> 4;
  const int b    = blockIdx.x >> 7;
  const int qt   = blockIdx.x & 127;
  const int qrow0 = b * 2048 + qt * 16;

  // Persistent Q fragments: A[m=l15][k=q4*8+t], 3 d-chunks of 32
  bf16x8 aq[3];
#pragma unroll
  for (int c = 0; c < 3; c++)
    aq[c] = *(const bf16x8*)
        &Q[(size_t)(qrow0 + l15) * 768 + h * 96 + c * 32 + q4 * 8];

  fx4 o[6];
#pragma unroll
  for (int j = 0; j < 6; j++) o[j] = (fx4){0.f, 0.f, 0.f, 0.f};

  const bf16* Vbase = Vt + (size_t)((b * 8 + h) * 96) * 2048;

  for (int kt = 0; kt < 32; kt++) {
    const int krow0 = b * 2048 + kt * 64;

    // ---- V fragments for THIS iteration, issued early (latency overlaps
    // QK + scatter; drained at the bar1 waitcnt).
    bf16x8 bv[2][6];
#pragma unroll
    for (int c2 = 0; c2 < 2; c2++)
#pragma unroll
      for (int j2 = 0; j2 < 6; j2++)
        bv[c2][j2] = *(const bf16x8*)
            &Vbase[(size_t)(j2 * 16 + l15) * 2048 + kt * 64 + c2 * 32 + q4 * 8];

    // ---- E = Q K^T : [16q x 64k]
    fx4 e[4];
    e[0] = e[1] = e[2] = e[3] = (fx4){0.f, 0.f, 0.f, 0.f};
#pragma unroll
    for (int c = 0; c < 3; c++) {
#pragma unroll
      for (int j = 0; j < 4; j++) {
        bf16x8 bk = *(const bf16x8*)
            &Kb[(size_t)(krow0 + j * 16 + l15) * 768 + h * 96 + c * 32 + q4 * 8];
        e[j] = MFMA16(aq[c], bk, e[j]);
      }
    }
    // Scatter E -> Ebuf[q*514 + h*64 + k]
#pragma unroll
    for (int j = 0; j < 4; j++)
#pragma unroll
      for (int r = 0; r < 4; r++)
        Ebuf[(q4 * 4 + r) * 514 + h * 64 + j * 16 + l15] = e[j][r];
    __syncthreads();

    // ---- Softmax over heads. 16q x 64k = 1024 pairs, 2 per thread.
#pragma unroll
    for (int pp = 0; pp < 2; pp++) {
      const int p = tid + pp * 512;
      const int q = p >> 6, k = p & 63;
      float v[8];
#pragma unroll
      for (int hh = 0; hh < 8; hh++) v[hh] = Ebuf[q * 514 + hh * 64 + k];
      float m = v[0];
#pragma unroll
      for (int hh = 1; hh < 8; hh++) m = fmaxf(m, v[hh]);
      float s = 0.f;
#pragma unroll
      for (int hh = 0; hh < 8; hh++) { v[hh] = __expf(v[hh] - m); s += v[hh]; }
      const float inv = 1.0f / (s * 27.712812921102035f);  // / sqrt(768)
#pragma unroll
      for (int hh = 0; hh < 8; hh++)
        Pbuf[hh * 1024 + q * 64 + k] = (bf16)(v[hh] * inv);
    }
    __syncthreads();

    // ---- O += P @ V
    bf16x8 ap[2];
#pragma unroll
    for (int c2 = 0; c2 < 2; c2++)
      ap[c2] = *(const bf16x8*)&Pbuf[h * 1024 + l15 * 64 + c2 * 32 + q4 * 8];
#pragma unroll
    for (int c2 = 0; c2 < 2; c2++)
#pragma unroll
      for (int j2 = 0; j2 < 6; j2++)
        o[j2] = MFMA16(ap[c2], bv[c2][j2], o[j2]);
    // Ebuf rewrite is gated by bar2 (softmax reads done); Pbuf rewrite by
    // the NEXT bar1 (ap reads drained by then).
  }

  // Write AO[qrow0 + q][h*96 + d]
#pragma unroll
  for (int j2 = 0; j2 < 6; j2++)
#pragma unroll
    for (int r = 0; r < 4; r++)
      AO[(size_t)(qrow0 + q4 * 4 + r) * 768 + h * 96 + j2 * 16 + l15] =
          (bf16)(o[j2][r]);
}

// ---------------------------------------------------------------------------
// Memory plan:
//   d_out (25.17 MB fp32) doubles as: xb (bf16, 12.58 MB) + K (bf16, 12.58 MB)
//   — both dead before the final projection overwrites d_out with fp32 result.
//   d_ws: Q (12.58 MB) + Vt (12.58 MB) = 25.2 MB (proven safe round 4).
//   AO aliases Q.
// ---------------------------------------------------------------------------
extern "C" void kernel_launch(void* const* d_in, const int* in_sizes, int n_in,
                              void* d_out, int out_size, void* d_ws,
                              size_t ws_size, hipStream_t stream) {
  const float* x  = (const float*)d_in[0];
  const float* Wq = (const float*)d_in[1];
  const float* bq = (const float*)d_in[2];
  const float* Wk = (const float*)d_in[3];
  const float* bk = (const float*)d_in[4];
  const float* Wv = (const float*)d_in[5];
  const float* bv = (const float*)d_in[6];
  const float* Wo = (const float*)d_in[7];
  const float* bo = (const float*)d_in[8];

  const size_t MN = (size_t)8192 * 768;
  bf16* xb = (bf16*)d_out;       // first half of d_out
  bf16* Kw = xb + MN;            // second half of d_out
  bf16* Q  = (bf16*)d_ws;
  bf16* Vt = Q + MN;
  bf16* AO = Q;                  // aliases Q

  cvt_x_kernel<<<6144, 256, 0, stream>>>(x, xb);

  dim3 ggrid(6, 64);  // (768/128, 8192/128)
  gemm_bt<0, 0><<<ggrid, 256, 0, stream>>>(xb, Wq, bq, Q);
  gemm_bt<0, 0><<<ggrid, 256, 0, stream>>>(xb, Wk, bk, Kw);
  gemm_bt<1, 0><<<ggrid, 256, 0, stream>>>(xb, Wv, bv, Vt);
  attn_kernel<<<512, 512, 0, stream>>>(Q, Kw, Vt, AO);
  gemm_bt<0, 1><<<ggrid, 256, 0, stream>>>(AO, Wo, bo, d_out);
}

// Round 6
// 537.286 us; speedup vs baseline: 1.0669x; 1.0669x over previous
//
#include <hip/hip_runtime.h>

typedef __bf16 bf16;
typedef __bf16 bf16x4 __attribute__((ext_vector_type(4)));
typedef __bf16 bf16x8 __attribute__((ext_vector_type(8)));
typedef float  fx4    __attribute__((ext_vector_type(4)));

#define MFMA16(a, b, c) __builtin_amdgcn_mfma_f32_16x16x32_bf16((a), (b), (c), 0, 0, 0)

// B=4, N=2048, E=768, H=8, D=96; M = B*N = 8192. User tensors fp32, out fp32.

// ---------------------------------------------------------------------------
// x (fp32) -> bf16, 4 elems/thread.
// ---------------------------------------------------------------------------
__global__ __launch_bounds__(256)
void cvt_x_kernel(const float* __restrict__ x, bf16* __restrict__ xb) {
  const int i = (blockIdx.x * 256 + threadIdx.x) * 4;
  float4 v = *(const float4*)&x[i];
  bf16x4 o;
  o[0] = (bf16)v.x; o[1] = (bf16)v.y; o[2] = (bf16)v.z; o[3] = (bf16)v.w;
  *(bf16x4*)&xb[i] = o;
}

// ---------------------------------------------------------------------------
// Fused QKV GEMM: one logical [8192 x 2304] GEMM over shared A=xb.
// blockIdx.x: 0-5 -> Q cols, 6-11 -> K cols, 12-17 -> V cols (transposed out).
// 1152 blocks = 4.5/CU (vs 1.5 for separate 768-wide GEMMs).
// Tile 128x128, BK=32, 4 waves 2x2, 4x4 MFMAs/wave.
// ---------------------------------------------------------------------------
__global__ __launch_bounds__(256)
void gemm_qkv(const bf16* __restrict__ A,
              const float* __restrict__ Wq, const float* __restrict__ Wk,
              const float* __restrict__ Wv,
              const float* __restrict__ bq, const float* __restrict__ bk,
              const float* __restrict__ bv,
              bf16* __restrict__ Qo, bf16* __restrict__ Ko,
              bf16* __restrict__ Vto) {
  constexpr int K = 768;
  __shared__ __align__(16) bf16 As[128 * 32];
  __shared__ __align__(16) bf16 Bs[128 * 32];

  const int tid  = threadIdx.x;
  const int wave = tid >> 6;
  const int lane = tid & 63;
  const int l15  = lane & 15;
  const int q4   = lane >> 4;
  const int wr   = wave >> 1;
  const int wc   = wave & 1;
  const int sel  = blockIdx.x / 6;            // 0=Q 1=K 2=V (block-uniform)
  const int cb0  = (blockIdx.x % 6) * 128;
  const int rb0  = blockIdx.y * 128;

  const float* W   = (sel == 0) ? Wq : (sel == 1) ? Wk : Wv;
  const float* bia = (sel == 0) ? bq : (sel == 1) ? bk : bv;

  fx4 acc[4][4];
#pragma unroll
  for (int i = 0; i < 4; i++)
#pragma unroll
    for (int j = 0; j < 4; j++) acc[i][j] = (fx4){0.f, 0.f, 0.f, 0.f};

  for (int k0 = 0; k0 < K; k0 += 32) {
    for (int c = tid; c < 512; c += 256) {
      const int row = c >> 2;
      const int kc  = (c & 3) << 3;
      *(uint4*)&As[row * 32 + kc] =
          *(const uint4*)&A[(size_t)(rb0 + row) * K + k0 + kc];
      const float* sb = W + (size_t)(cb0 + row) * K + k0 + kc;
      bf16x8 pb;
#pragma unroll
      for (int t = 0; t < 8; t++) pb[t] = (bf16)sb[t];
      *(bf16x8*)&Bs[row * 32 + kc] = pb;
    }
    __syncthreads();

    bf16x8 a[4], b[4];
#pragma unroll
    for (int i = 0; i < 4; i++)
      a[i] = *(const bf16x8*)&As[(wr * 64 + i * 16 + l15) * 32 + q4 * 8];
#pragma unroll
    for (int j = 0; j < 4; j++)
      b[j] = *(const bf16x8*)&Bs[(wc * 64 + j * 16 + l15) * 32 + q4 * 8];
#pragma unroll
    for (int i = 0; i < 4; i++)
#pragma unroll
      for (int j = 0; j < 4; j++)
        acc[i][j] = MFMA16(a[i], b[j], acc[i][j]);
    __syncthreads();
  }

  // Epilogue. C/D layout: col = lane&15, row = (lane>>4)*4 + reg.
  const int cb = cb0 + wc * 64;
  const int rb = rb0 + wr * 64;
  bf16* Co = (sel == 0) ? Qo : Ko;
#pragma unroll
  for (int j = 0; j < 4; j++) {
    const int o  = cb + j * 16 + l15;
    const float bj = bia[o];
#pragma unroll
    for (int i = 0; i < 4; i++) {
      const int r0 = rb + i * 16 + q4 * 4;
      if (sel == 2) {
        // Vt[(batch*768 + o)*2048 + n]
        const int bb = r0 >> 11;
        const int n0 = r0 & 2047;
        bf16x4 pk;
#pragma unroll
        for (int r = 0; r < 4; r++) pk[r] = (bf16)(acc[i][j][r] + bj);
        *(bf16x4*)&Vto[((size_t)(bb * 768 + o)) * 2048 + n0] = pk;
      } else {
#pragma unroll
        for (int r = 0; r < 4; r++)
          Co[(size_t)(r0 + r) * 768 + o] = (bf16)(acc[i][j][r] + bj);
      }
    }
  }
}

// ---------------------------------------------------------------------------
// Output projection: out[M,768] fp32 = AO[M,768]bf16 @ Wo^T + bo.
// ---------------------------------------------------------------------------
__global__ __launch_bounds__(256)
void gemm_o(const bf16* __restrict__ A, const float* __restrict__ W,
            const float* __restrict__ bias, float* __restrict__ C) {
  constexpr int K = 768;
  __shared__ __align__(16) bf16 As[128 * 32];
  __shared__ __align__(16) bf16 Bs[128 * 32];

  const int tid  = threadIdx.x;
  const int wave = tid >> 6;
  const int lane = tid & 63;
  const int l15  = lane & 15;
  const int q4   = lane >> 4;
  const int wr   = wave >> 1;
  const int wc   = wave & 1;
  const int rb0  = blockIdx.y * 128;
  const int cb0  = blockIdx.x * 128;

  fx4 acc[4][4];
#pragma unroll
  for (int i = 0; i < 4; i++)
#pragma unroll
    for (int j = 0; j < 4; j++) acc[i][j] = (fx4){0.f, 0.f, 0.f, 0.f};

  for (int k0 = 0; k0 < K; k0 += 32) {
    for (int c = tid; c < 512; c += 256) {
      const int row = c >> 2;
      const int kc  = (c & 3) << 3;
      *(uint4*)&As[row * 32 + kc] =
          *(const uint4*)&A[(size_t)(rb0 + row) * K + k0 + kc];
      const float* sb = W + (size_t)(cb0 + row) * K + k0 + kc;
      bf16x8 pb;
#pragma unroll
      for (int t = 0; t < 8; t++) pb[t] = (bf16)sb[t];
      *(bf16x8*)&Bs[row * 32 + kc] = pb;
    }
    __syncthreads();

    bf16x8 a[4], b[4];
#pragma unroll
    for (int i = 0; i < 4; i++)
      a[i] = *(const bf16x8*)&As[(wr * 64 + i * 16 + l15) * 32 + q4 * 8];
#pragma unroll
    for (int j = 0; j < 4; j++)
      b[j] = *(const bf16x8*)&Bs[(wc * 64 + j * 16 + l15) * 32 + q4 * 8];
#pragma unroll
    for (int i = 0; i < 4; i++)
#pragma unroll
      for (int j = 0; j < 4; j++)
        acc[i][j] = MFMA16(a[i], b[j], acc[i][j]);
    __syncthreads();
  }

  const int cb = cb0 + wc * 64;
  const int rb = rb0 + wr * 64;
#pragma unroll
  for (int j = 0; j < 4; j++) {
    const int o  = cb + j * 16 + l15;
    const float bj = bias[o];
#pragma unroll
    for (int i = 0; i < 4; i++) {
      const int r0 = rb + i * 16 + q4 * 4;
#pragma unroll
      for (int r = 0; r < 4; r++)
        C[(size_t)(r0 + r) * 768 + o] = acc[i][j][r] + bj;
    }
  }
}

// ---------------------------------------------------------------------------
// Attention, softmax over HEADS — in-register cross-head softmax.
// Wave w owns k-slice w (16 keys) of a TK=128 tile and iterates ALL 8 heads:
// each lane's 8 QK accumulators hold E_h at the SAME (q,k) -> softmax over h
// is pure VALU, no LDS, no barrier. Only the P C->A layout transpose goes
// through LDS (2 barriers per TK=128 iter; 16 iters total vs 128 barriers
// in the round-4 design). Q tile (16x768) staged once in LDS.
// Grid = 512 blocks (b, qt16) = 2 blocks/CU at 59.6 KB LDS, VGPR<=128.
// AO aliases Q: block reads only its own 16 Q rows (into LDS, before loop),
// writes only those rows after the loop.
// ---------------------------------------------------------------------------
__global__ __launch_bounds__(512, 4)
void attn_kernel(const bf16* Q, const bf16* __restrict__ Kb,
                 const bf16* __restrict__ Vt, bf16* AO) {
  __shared__ __align__(16) bf16 Qbuf[16 * 776];      // 24.8 KB, stride 776 (16B-aligned rows)
  __shared__ __align__(16) bf16 Pbuf[8 * 16 * 136];  // 34.8 KB, [h][q][k], stride 136

  const int tid  = threadIdx.x;
  const int w    = tid >> 6;      // wave = k-slice (QK) and head (PV)
  const int lane = tid & 63;
  const int l15  = lane & 15;
  const int q4   = lane >> 4;
  const int b    = blockIdx.x >> 7;
  const int qt   = blockIdx.x & 127;
  const int qrow0 = b * 2048 + qt * 16;

  // Stage the 16 Q rows (all heads) into LDS once.
  for (int c = tid; c < 16 * 96; c += 512) {
    const int row = c / 96;
    const int col = (c % 96) * 8;
    *(bf16x8*)&Qbuf[row * 776 + col] =
        *(const bf16x8*)&Q[(size_t)(qrow0 + row) * 768 + col];
  }
  __syncthreads();

  fx4 o[6];
#pragma unroll
  for (int j = 0; j < 6; j++) o[j] = (fx4){0.f, 0.f, 0.f, 0.f};

  const bf16* Vbase = Vt + (size_t)((b * 8 + w) * 96) * 2048;

  for (int kt = 0; kt < 16; kt++) {
    // This lane's K row for the QK phase (wave w covers keys kt*128+w*16..+15)
    const size_t krow = (size_t)(b * 2048 + kt * 128 + w * 16 + l15) * 768;

    // ---- E_h = Q K^T for all 8 heads, 16q x 16k per wave, in-register.
    fx4 e[8];
#pragma unroll
    for (int h = 0; h < 8; h++) e[h] = (fx4){0.f, 0.f, 0.f, 0.f};
#pragma unroll
    for (int h = 0; h < 8; h++) {
#pragma unroll
      for (int c = 0; c < 3; c++) {
        bf16x8 aq = *(const bf16x8*)&Qbuf[l15 * 776 + h * 96 + c * 32 + q4 * 8];
        bf16x8 bk = *(const bf16x8*)&Kb[krow + h * 96 + c * 32 + q4 * 8];
        e[h] = MFMA16(aq, bk, e[h]);
      }
    }

    // ---- In-register softmax over h (each lane: same (q,k) across e[0..7]),
    // scatter P (bf16) to LDS [h][q][k] for the C->A layout transpose.
#pragma unroll
    for (int r = 0; r < 4; r++) {
      float m = e[0][r];
#pragma unroll
      for (int h = 1; h < 8; h++) m = fmaxf(m, e[h][r]);
      float p[8], s = 0.f;
#pragma unroll
      for (int h = 0; h < 8; h++) { p[h] = __expf(e[h][r] - m); s += p[h]; }
      const float inv = 1.0f / (s * 27.712812921102035f);  // / sqrt(768)
#pragma unroll
      for (int h = 0; h < 8; h++)
        Pbuf[h * 2176 + (q4 * 4 + r) * 136 + w * 16 + l15] =
            (bf16)(p[h] * inv);
    }
    __syncthreads();

    // ---- PV: wave w = head w. O[16q x 96d] += P[16 x 128] @ V[128 x 96].
#pragma unroll
    for (int c2 = 0; c2 < 4; c2++) {
      bf16x8 ap = *(const bf16x8*)&Pbuf[w * 2176 + l15 * 136 + c2 * 32 + q4 * 8];
#pragma unroll
      for (int j2 = 0; j2 < 6; j2++) {
        bf16x8 bv = *(const bf16x8*)
            &Vbase[(size_t)(j2 * 16 + l15) * 2048 + kt * 128 + c2 * 32 + q4 * 8];
        o[j2] = MFMA16(ap, bv, o[j2]);
      }
    }
    __syncthreads();  // protect Pbuf rewrite next iteration
  }

  // Write AO[qrow0 + q][w*96 + d]
#pragma unroll
  for (int j2 = 0; j2 < 6; j2++)
#pragma unroll
    for (int r = 0; r < 4; r++)
      AO[(size_t)(qrow0 + q4 * 4 + r) * 768 + w * 96 + j2 * 16 + l15] =
          (bf16)(o[j2][r]);
}

// ---------------------------------------------------------------------------
// Memory plan (unchanged, proven): d_out = xb (bf16) + Kw (bf16), both dead
// before the final projection overwrites d_out fp32. ws = Q + Vt (25.2 MB).
// AO aliases Q.
// ---------------------------------------------------------------------------
extern "C" void kernel_launch(void* const* d_in, const int* in_sizes, int n_in,
                              void* d_out, int out_size, void* d_ws,
                              size_t ws_size, hipStream_t stream) {
  const float* x  = (const float*)d_in[0];
  const float* Wq = (const float*)d_in[1];
  const float* bq = (const float*)d_in[2];
  const float* Wk = (const float*)d_in[3];
  const float* bk = (const float*)d_in[4];
  const float* Wv = (const float*)d_in[5];
  const float* bv = (const float*)d_in[6];
  const float* Wo = (const float*)d_in[7];
  const float* bo = (const float*)d_in[8];

  const size_t MN = (size_t)8192 * 768;
  bf16* xb = (bf16*)d_out;
  bf16* Kw = xb + MN;
  bf16* Q  = (bf16*)d_ws;
  bf16* Vt = Q + MN;
  bf16* AO = Q;  // aliases Q

  cvt_x_kernel<<<6144, 256, 0, stream>>>(x, xb);
  dim3 qkvgrid(18, 64);
  gemm_qkv<<<qkvgrid, 256, 0, stream>>>(xb, Wq, Wk, Wv, bq, bk, bv, Q, Kw, Vt);
  attn_kernel<<<512, 512, 0, stream>>>(Q, Kw, Vt, AO);
  dim3 ogrid(6, 64);
  gemm_o<<<ogrid, 256, 0, stream>>>(AO, Wo, bo, (float*)d_out);
}

// Round 7
// 387.722 us; speedup vs baseline: 1.4784x; 1.3857x over previous
//
#include <hip/hip_runtime.h>

typedef __bf16 bf16;
typedef __bf16 bf16x4 __attribute__((ext_vector_type(4)));
typedef __bf16 bf16x8 __attribute__((ext_vector_type(8)));
typedef float  fx4    __attribute__((ext_vector_type(4)));

#define MFMA16(a, b, c) __builtin_amdgcn_mfma_f32_16x16x32_bf16((a), (b), (c), 0, 0, 0)

// B=4, N=2048, E=768, H=8, D=96; M = B*N = 8192. User tensors fp32, out fp32.

// ---------------------------------------------------------------------------
// x (fp32) -> bf16, 4 elems/thread.
// ---------------------------------------------------------------------------
__global__ __launch_bounds__(256)
void cvt_x_kernel(const float* __restrict__ x, bf16* __restrict__ xb) {
  const int i = (blockIdx.x * 256 + threadIdx.x) * 4;
  float4 v = *(const float4*)&x[i];
  bf16x4 o;
  o[0] = (bf16)v.x; o[1] = (bf16)v.y; o[2] = (bf16)v.z; o[3] = (bf16)v.w;
  *(bf16x4*)&xb[i] = o;
}

// ---------------------------------------------------------------------------
// Fused QKV GEMM (proven round 6: 1152 blocks = 4.5/CU).
// blockIdx.x: 0-5 -> Q cols, 6-11 -> K cols, 12-17 -> V cols (transposed out).
// Tile 128x128, BK=32, 4 waves 2x2, 4x4 MFMAs/wave.
// ---------------------------------------------------------------------------
__global__ __launch_bounds__(256)
void gemm_qkv(const bf16* __restrict__ A,
              const float* __restrict__ Wq, const float* __restrict__ Wk,
              const float* __restrict__ Wv,
              const float* __restrict__ bq, const float* __restrict__ bk,
              const float* __restrict__ bv,
              bf16* __restrict__ Qo, bf16* __restrict__ Ko,
              bf16* __restrict__ Vto) {
  constexpr int K = 768;
  __shared__ __align__(16) bf16 As[128 * 32];
  __shared__ __align__(16) bf16 Bs[128 * 32];

  const int tid  = threadIdx.x;
  const int wave = tid >> 6;
  const int lane = tid & 63;
  const int l15  = lane & 15;
  const int q4   = lane >> 4;
  const int wr   = wave >> 1;
  const int wc   = wave & 1;
  const int sel  = blockIdx.x / 6;            // 0=Q 1=K 2=V (block-uniform)
  const int cb0  = (blockIdx.x % 6) * 128;
  const int rb0  = blockIdx.y * 128;

  const float* W   = (sel == 0) ? Wq : (sel == 1) ? Wk : Wv;
  const float* bia = (sel == 0) ? bq : (sel == 1) ? bk : bv;

  fx4 acc[4][4];
#pragma unroll
  for (int i = 0; i < 4; i++)
#pragma unroll
    for (int j = 0; j < 4; j++) acc[i][j] = (fx4){0.f, 0.f, 0.f, 0.f};

  for (int k0 = 0; k0 < K; k0 += 32) {
    for (int c = tid; c < 512; c += 256) {
      const int row = c >> 2;
      const int kc  = (c & 3) << 3;
      *(uint4*)&As[row * 32 + kc] =
          *(const uint4*)&A[(size_t)(rb0 + row) * K + k0 + kc];
      const float* sb = W + (size_t)(cb0 + row) * K + k0 + kc;
      bf16x8 pb;
#pragma unroll
      for (int t = 0; t < 8; t++) pb[t] = (bf16)sb[t];
      *(bf16x8*)&Bs[row * 32 + kc] = pb;
    }
    __syncthreads();

    bf16x8 a[4], b[4];
#pragma unroll
    for (int i = 0; i < 4; i++)
      a[i] = *(const bf16x8*)&As[(wr * 64 + i * 16 + l15) * 32 + q4 * 8];
#pragma unroll
    for (int j = 0; j < 4; j++)
      b[j] = *(const bf16x8*)&Bs[(wc * 64 + j * 16 + l15) * 32 + q4 * 8];
#pragma unroll
    for (int i = 0; i < 4; i++)
#pragma unroll
      for (int j = 0; j < 4; j++)
        acc[i][j] = MFMA16(a[i], b[j], acc[i][j]);
    __syncthreads();
  }

  const int cb = cb0 + wc * 64;
  const int rb = rb0 + wr * 64;
  bf16* Co = (sel == 0) ? Qo : Ko;
#pragma unroll
  for (int j = 0; j < 4; j++) {
    const int o  = cb + j * 16 + l15;
    const float bj = bia[o];
#pragma unroll
    for (int i = 0; i < 4; i++) {
      const int r0 = rb + i * 16 + q4 * 4;
      if (sel == 2) {
        const int bb = r0 >> 11;
        const int n0 = r0 & 2047;
        bf16x4 pk;
#pragma unroll
        for (int r = 0; r < 4; r++) pk[r] = (bf16)(acc[i][j][r] + bj);
        *(bf16x4*)&Vto[((size_t)(bb * 768 + o)) * 2048 + n0] = pk;
      } else {
#pragma unroll
        for (int r = 0; r < 4; r++)
          Co[(size_t)(r0 + r) * 768 + o] = (bf16)(acc[i][j][r] + bj);
      }
    }
  }
}

// ---------------------------------------------------------------------------
// Output projection: out[M,768] fp32 = AO[M,768]bf16 @ Wo^T + bo.
// ---------------------------------------------------------------------------
__global__ __launch_bounds__(256)
void gemm_o(const bf16* __restrict__ A, const float* __restrict__ W,
            const float* __restrict__ bias, float* __restrict__ C) {
  constexpr int K = 768;
  __shared__ __align__(16) bf16 As[128 * 32];
  __shared__ __align__(16) bf16 Bs[128 * 32];

  const int tid  = threadIdx.x;
  const int wave = tid >> 6;
  const int lane = tid & 63;
  const int l15  = lane & 15;
  const int q4   = lane >> 4;
  const int wr   = wave >> 1;
  const int wc   = wave & 1;
  const int rb0  = blockIdx.y * 128;
  const int cb0  = blockIdx.x * 128;

  fx4 acc[4][4];
#pragma unroll
  for (int i = 0; i < 4; i++)
#pragma unroll
    for (int j = 0; j < 4; j++) acc[i][j] = (fx4){0.f, 0.f, 0.f, 0.f};

  for (int k0 = 0; k0 < K; k0 += 32) {
    for (int c = tid; c < 512; c += 256) {
      const int row = c >> 2;
      const int kc  = (c & 3) << 3;
      *(uint4*)&As[row * 32 + kc] =
          *(const uint4*)&A[(size_t)(rb0 + row) * K + k0 + kc];
      const float* sb = W + (size_t)(cb0 + row) * K + k0 + kc;
      bf16x8 pb;
#pragma unroll
      for (int t = 0; t < 8; t++) pb[t] = (bf16)sb[t];
      *(bf16x8*)&Bs[row * 32 + kc] = pb;
    }
    __syncthreads();

    bf16x8 a[4], b[4];
#pragma unroll
    for (int i = 0; i < 4; i++)
      a[i] = *(const bf16x8*)&As[(wr * 64 + i * 16 + l15) * 32 + q4 * 8];
#pragma unroll
    for (int j = 0; j < 4; j++)
      b[j] = *(const bf16x8*)&Bs[(wc * 64 + j * 16 + l15) * 32 + q4 * 8];
#pragma unroll
    for (int i = 0; i < 4; i++)
#pragma unroll
      for (int j = 0; j < 4; j++)
        acc[i][j] = MFMA16(a[i], b[j], acc[i][j]);
    __syncthreads();
  }

  const int cb = cb0 + wc * 64;
  const int rb = rb0 + wr * 64;
#pragma unroll
  for (int j = 0; j < 4; j++) {
    const int o  = cb + j * 16 + l15;
    const float bj = bias[o];
#pragma unroll
    for (int i = 0; i < 4; i++) {
      const int r0 = rb + i * 16 + q4 * 4;
#pragma unroll
      for (int r = 0; r < 4; r++)
        C[(size_t)(r0 + r) * 768 + o] = acc[i][j][r] + bj;
    }
  }
}

// ---------------------------------------------------------------------------
// Attention, softmax over HEADS (dim=1), / sqrt(768).
// Round-4 structure (proven 258 us): wave = head, TQ=32, TK=32, grid 256,
// LDS cross-head softmax, 2 barriers/iter. ONE change: all 12 global
// fragment loads (6 K + 6 V) are batched into register arrays at the top of
// each iteration -> one vmcnt drain instead of 12 serialized load-use chains.
// __launch_bounds__(512,2) lifts the VGPR cap to 256 so the batch stays in
// registers (round 4/6 had VGPR=52..64 -> compiler serialized every load).
// V regs stay live across both barriers, consumed in PV.
// Ebuf q-stride 260: scatter becomes 2-way (free) instead of 4-way.
// AO aliases Q: block reads only its own 32 Q rows before the loop, writes
// only those rows after it.
// ---------------------------------------------------------------------------
__global__ __launch_bounds__(512, 2)
void attn_kernel(const bf16* Q, const bf16* __restrict__ Kb,
                 const bf16* __restrict__ Vt, bf16* AO) {
  __shared__ __align__(16) float Ebuf[32 * 260];     // [q][h*32+k], 33.3 KB
  __shared__ __align__(16) bf16  Pbuf[8 * 32 * 32];  // [h][q][k],   16 KB

  const int tid  = threadIdx.x;
  const int h    = tid >> 6;
  const int lane = tid & 63;
  const int l15  = lane & 15;
  const int q4   = lane >> 4;
  const int b    = blockIdx.x >> 6;
  const int qt   = blockIdx.x & 63;
  const int qrow0 = b * 2048 + qt * 32;

  // Persistent Q fragments: 2 q-16tiles x 3 d-chunks.
  bf16x8 aq[2][3];
#pragma unroll
  for (int i = 0; i < 2; i++)
#pragma unroll
    for (int c = 0; c < 3; c++)
      aq[i][c] = *(const bf16x8*)
          &Q[(size_t)(qrow0 + i * 16 + l15) * 768 + h * 96 + c * 32 + q4 * 8];

  fx4 o[2][6];
#pragma unroll
  for (int i = 0; i < 2; i++)
#pragma unroll
    for (int j = 0; j < 6; j++) o[i][j] = (fx4){0.f, 0.f, 0.f, 0.f};

  // Per-lane fixed base pointers (hoisted out of the loop).
  const bf16* Kp0 = Kb + (size_t)(b * 2048 + l15) * 768 + h * 96 + q4 * 8;
  const bf16* Vp0 = Vt + (size_t)((b * 8 + h) * 96 + l15) * 2048 + q4 * 8;

  for (int kt = 0; kt < 64; kt++) {
    // ---- Batched loads: 6 K-fragments + 6 V-fragments, all independent,
    // all in flight together.
    bf16x8 bk[2][3], bv[6];
    const bf16* Kp = Kp0 + (size_t)(kt * 32) * 768;
#pragma unroll
    for (int j = 0; j < 2; j++)
#pragma unroll
      for (int c = 0; c < 3; c++)
        bk[j][c] = *(const bf16x8*)(Kp + (size_t)(j * 16) * 768 + c * 32);
#pragma unroll
    for (int j2 = 0; j2 < 6; j2++)
      bv[j2] = *(const bf16x8*)(Vp0 + (size_t)(j2 * 16) * 2048 + kt * 32);

    // ---- E = Q K^T : [32q x 32k] for this head.
    fx4 e[2][2];
    e[0][0] = e[0][1] = e[1][0] = e[1][1] = (fx4){0.f, 0.f, 0.f, 0.f};
#pragma unroll
    for (int c = 0; c < 3; c++)
#pragma unroll
      for (int j = 0; j < 2; j++) {
        e[0][j] = MFMA16(aq[0][c], bk[j][c], e[0][j]);
        e[1][j] = MFMA16(aq[1][c], bk[j][c], e[1][j]);
      }

    // Scatter E -> Ebuf[q*260 + h*32 + k]  (2-way banked: free)
#pragma unroll
    for (int i = 0; i < 2; i++)
#pragma unroll
      for (int j = 0; j < 2; j++)
#pragma unroll
        for (int r = 0; r < 4; r++)
          Ebuf[(i * 16 + q4 * 4 + r) * 260 + h * 32 + j * 16 + l15] = e[i][j][r];
    __syncthreads();

    // ---- Softmax over heads. 32q x 32k = 1024 pairs, 2 per thread.
#pragma unroll
    for (int pp = 0; pp < 2; pp++) {
      const int p = tid + pp * 512;
      const int q = p >> 5, k = p & 31;
      float v[8];
#pragma unroll
      for (int hh = 0; hh < 8; hh++) v[hh] = Ebuf[q * 260 + hh * 32 + k];
      float m = v[0];
#pragma unroll
      for (int hh = 1; hh < 8; hh++) m = fmaxf(m, v[hh]);
      float s = 0.f;
#pragma unroll
      for (int hh = 0; hh < 8; hh++) { v[hh] = __expf(v[hh] - m); s += v[hh]; }
      const float inv = 1.0f / (s * 27.712812921102035f);  // / sqrt(768)
#pragma unroll
      for (int hh = 0; hh < 8; hh++)
        Pbuf[hh * 1024 + q * 32 + k] = (bf16)(v[hh] * inv);
    }
    __syncthreads();

    // ---- O += P @ V  (V already in registers since the top of the iter).
    bf16x8 ap[2];
#pragma unroll
    for (int i = 0; i < 2; i++)
      ap[i] = *(const bf16x8*)&Pbuf[h * 1024 + (i * 16 + l15) * 32 + q4 * 8];
#pragma unroll
    for (int j2 = 0; j2 < 6; j2++) {
      o[0][j2] = MFMA16(ap[0], bv[j2], o[0][j2]);
      o[1][j2] = MFMA16(ap[1], bv[j2], o[1][j2]);
    }
    // Ebuf rewrite gated by bar2; Pbuf rewrite by next bar1.
  }

  // Write AO[qrow0 + q][h*96 + d]
#pragma unroll
  for (int i = 0; i < 2; i++)
#pragma unroll
    for (int j2 = 0; j2 < 6; j2++)
#pragma unroll
      for (int r = 0; r < 4; r++)
        AO[(size_t)(qrow0 + i * 16 + q4 * 4 + r) * 768 + h * 96 + j2 * 16 + l15] =
            (bf16)(o[i][j2][r]);
}

// ---------------------------------------------------------------------------
// Memory plan (proven): d_out = xb (bf16) + Kw (bf16), both dead before the
// final projection overwrites d_out fp32. ws = Q + Vt (25.2 MB). AO aliases Q.
// ---------------------------------------------------------------------------
extern "C" void kernel_launch(void* const* d_in, const int* in_sizes, int n_in,
                              void* d_out, int out_size, void* d_ws,
                              size_t ws_size, hipStream_t stream) {
  const float* x  = (const float*)d_in[0];
  const float* Wq = (const float*)d_in[1];
  const float* bq = (const float*)d_in[2];
  const float* Wk = (const float*)d_in[3];
  const float* bk = (const float*)d_in[4];
  const float* Wv = (const float*)d_in[5];
  const float* bv = (const float*)d_in[6];
  const float* Wo = (const float*)d_in[7];
  const float* bo = (const float*)d_in[8];

  const size_t MN = (size_t)8192 * 768;
  bf16* xb = (bf16*)d_out;
  bf16* Kw = xb + MN;
  bf16* Q  = (bf16*)d_ws;
  bf16* Vt = Q + MN;
  bf16* AO = Q;  // aliases Q

  cvt_x_kernel<<<6144, 256, 0, stream>>>(x, xb);
  dim3 qkvgrid(18, 64);
  gemm_qkv<<<qkvgrid, 256, 0, stream>>>(xb, Wq, Wk, Wv, bq, bk, bv, Q, Kw, Vt);
  attn_kernel<<<256, 512, 0, stream>>>(Q, Kw, Vt, AO);
  dim3 ogrid(6, 64);
  gemm_o<<<ogrid, 256, 0, stream>>>(AO, Wo, bo, (float*)d_out);
}